// Round 8
// baseline (196.097 us; speedup 1.0000x reference)
//
#include <hip/hip_runtime.h>

typedef __bf16 bf16x8 __attribute__((ext_vector_type(8)));
typedef float f32x4 __attribute__((ext_vector_type(4)));

#define BS 2
#define SEQ 2048
#define DM 1024
#define NH 16
#define DKH 64
#define GM 4096
#define GN 1024
#define GK 1024
#define NEGV (-1e9f)

// ws layout (ushort units). At aliases the (now unused) low region.
#define OFF_QH 16777216u
#define OFF_KC 20971520u
#define OFF_VT 25165824u
#define OFF_AT 0u

#if __has_builtin(__builtin_amdgcn_exp2f)
#define EXP2(x) __builtin_amdgcn_exp2f(x)
#else
static __device__ __forceinline__ float EXP2(float x) {
    float r;
    asm volatile("v_exp_f32 %0, %1" : "=v"(r) : "v"(x));
    return r;
}
#endif

__device__ __forceinline__ unsigned cvt_pk(float lo, float hi) {
    unsigned r;
    asm volatile("v_cvt_pk_bf16_f32 %0, %1, %2" : "=v"(r) : "v"(lo), "v"(hi));
    return r;
}

__device__ __forceinline__ unsigned short f2b(float f) {
    unsigned u = __builtin_bit_cast(unsigned, f);
    u += 0x7fffu + ((u >> 16) & 1u);
    return (unsigned short)(u >> 16);
}

typedef const __attribute__((address_space(1))) unsigned int* gas_t;
typedef __attribute__((address_space(3))) unsigned int* las_t;

__device__ __forceinline__ void gload_lds16(const ushort* g, ushort* l) {
    __builtin_amdgcn_global_load_lds((gas_t)(const void*)g, (las_t)(void*)l, 16, 0, 0);
}

// Per-batch compaction: cpos[b][s] = compact index (or -1); mbuf[b] = count.
__global__ __launch_bounds__(256)
void scan_kernel(const int* __restrict__ mask, int* __restrict__ cpos, int* __restrict__ mbuf)
{
    const int b = blockIdx.x;
    const int* mp = mask + (size_t)b * SEQ;
    const int tid = threadIdx.x;
    const int lane = tid & 63, w = tid >> 6;
    int v[8];
    int cnt = 0;
#pragma unroll
    for (int j = 0; j < 8; ++j) { v[j] = mp[tid * 8 + j]; cnt += (v[j] != 0); }
    int inc = cnt;
#pragma unroll
    for (int d = 1; d < 64; d <<= 1) {
        int t = __shfl_up(inc, d);
        if (lane >= d) inc += t;
    }
    __shared__ int wsum[4];
    if (lane == 63) wsum[w] = inc;
    __syncthreads();
    int base = inc - cnt;
    for (int i = 0; i < w; ++i) base += wsum[i];
    int c = base;
    int* ob = cpos + (size_t)b * SEQ;
#pragma unroll
    for (int j = 0; j < 8; ++j) {
        ob[tid * 8 + j] = (v[j] != 0) ? c : -1;
        c += (v[j] != 0);
    }
    if (tid == 255) mbuf[b] = base + cnt;
}

// ---------------- fused fp32->bf16 128x128 GEMM (C = A @ B^T) ----------------
// Reg-staged: global fp32 loads (issued before compute of current tile),
// cvt_pk -> XOR-swizzled ds_write after compute, one __syncthreads per K-tile.
// 2 wgs/CU resident (64KB LDS). PROJ: z=0 Qh (scaled), z=1 Kc compact, z=2 sigma V^T.
// !PROJ: A = At bf16, B = Wo fp32, fp32 out.
template<bool PROJ>
__global__ __launch_bounds__(256, 2)
void gemm_fused(const float* __restrict__ qin, const float* __restrict__ kin,
                const float* __restrict__ vin, const float* __restrict__ wqp,
                const float* __restrict__ wkp, const float* __restrict__ wvp,
                const float* __restrict__ wop, ushort* __restrict__ ws,
                float* __restrict__ of, const int* __restrict__ cpos)
{
    __shared__ __align__(16) ushort lA[2][128 * 64];
    __shared__ __align__(16) ushort lB[2][128 * 64];

    const int z = PROJ ? blockIdx.z : 0;
    const float* Af = nullptr;
    const ushort* Ab = nullptr;
    const float* Bf;
    if (PROJ) {
        Af = (z == 0) ? qin : (z == 1) ? kin : vin;
        Bf = (z == 0) ? wqp : (z == 1) ? wkp : wvp;
    } else {
        Ab = ws + OFF_AT;
        Bf = wop;
    }

    const int tid = threadIdx.x;
    const int lane = tid & 63, wid = tid >> 6;
    const int wr = wid >> 1, wc = wid & 1;
    const int lr = lane & 15, lg = lane >> 4;
    const int lin = blockIdx.y * 8 + blockIdx.x;
    const int swz = (lin & 7) * 32 + (lin >> 3);   // XCD-aware
    const int m0 = (swz >> 3) * 128, n0 = (swz & 7) * 128;
    const int srow = tid >> 1, sch = tid & 1;      // staging: row, col-half
    const int swb = srow & 7;                      // staging row-XOR

    f32x4 acc[4][4] = {};
    float4 ar[8], br[8];
    uint4 arb[4];

    auto LOAD = [&](int t) {
        const int k0 = t * 64;
        if (PROJ) {
#pragma unroll
            for (int m = 0; m < 8; ++m)
                ar[m] = *(const float4*)(Af + (size_t)(m0 + srow) * GK + k0 + sch * 32 + m * 4);
        } else {
#pragma unroll
            for (int m = 0; m < 4; ++m)
                arb[m] = *(const uint4*)(Ab + (size_t)(m0 + srow) * GK + k0 + sch * 32 + m * 8);
        }
#pragma unroll
        for (int m = 0; m < 8; ++m)
            br[m] = *(const float4*)(Bf + (size_t)(n0 + srow) * GK + k0 + sch * 32 + m * 4);
    };

    auto WRITE = [&](int s) {
#pragma unroll
        for (int m = 0; m < 4; ++m) {
            uint4 w;
            if (PROJ) {
                w.x = cvt_pk(ar[2 * m].x, ar[2 * m].y);
                w.y = cvt_pk(ar[2 * m].z, ar[2 * m].w);
                w.z = cvt_pk(ar[2 * m + 1].x, ar[2 * m + 1].y);
                w.w = cvt_pk(ar[2 * m + 1].z, ar[2 * m + 1].w);
            } else {
                w = arb[m];
            }
            *(uint4*)&lA[s][srow * 64 + (((sch * 4 + m) ^ swb) * 8)] = w;
            uint4 wb;
            wb.x = cvt_pk(br[2 * m].x, br[2 * m].y);
            wb.y = cvt_pk(br[2 * m].z, br[2 * m].w);
            wb.z = cvt_pk(br[2 * m + 1].x, br[2 * m + 1].y);
            wb.w = cvt_pk(br[2 * m + 1].z, br[2 * m + 1].w);
            *(uint4*)&lB[s][srow * 64 + (((sch * 4 + m) ^ swb) * 8)] = wb;
        }
    };

    LOAD(0);
    WRITE(0);
    __syncthreads();

    for (int t = 0; t < 16; ++t) {
        const int cur = t & 1;
        if (t < 15) LOAD(t + 1);           // T14: issue early, lands under compute
#pragma unroll
        for (int kk = 0; kk < 2; ++kk) {
            bf16x8 af[4], bfr[4];
#pragma unroll
            for (int i = 0; i < 4; ++i) {
                const int rowa = wr * 64 + i * 16 + lr;
                af[i]  = *(const bf16x8*)&lA[cur][rowa * 64 + (((kk * 4 + lg) ^ (rowa & 7)) * 8)];
                const int rowb = wc * 64 + i * 16 + lr;
                bfr[i] = *(const bf16x8*)&lB[cur][rowb * 64 + (((kk * 4 + lg) ^ (rowb & 7)) * 8)];
            }
#pragma unroll
            for (int i = 0; i < 4; ++i)
#pragma unroll
                for (int j = 0; j < 4; ++j)
                    acc[i][j] = __builtin_amdgcn_mfma_f32_16x16x32_bf16(af[i], bfr[j], acc[i][j], 0, 0, 0);
        }
        if (t < 15) WRITE(cur ^ 1);        // write late, into the idle slot
        __syncthreads();
    }

    if (PROJ) {
        const float scale = (z == 0) ? 0.125f * 1.44269504088896f : 1.0f;  // 1/sqrt(64)*log2e
        ushort* qh  = ws + OFF_QH;
        ushort* kc  = ws + OFF_KC;
        ushort* vtp = ws + OFF_VT;
#pragma unroll
        for (int i = 0; i < 4; ++i) {
#pragma unroll
            for (int r = 0; r < 4; ++r) {
                int row = m0 + wr * 64 + i * 16 + lg * 4 + r;
                int b = row >> 11, s = row & 2047;
                if (z == 0) {
#pragma unroll
                    for (int j = 0; j < 4; ++j) {
                        int col = n0 + wc * 64 + j * 16 + lr;
                        qh[(((size_t)b * NH + (col >> 6)) * SEQ + s) * DKH + (col & 63)] =
                            f2b(acc[i][j][r] * scale);
                    }
                } else {
                    int c = cpos[b * SEQ + s];
                    if (c >= 0) {
                        if (z == 1) {
#pragma unroll
                            for (int j = 0; j < 4; ++j) {
                                int col = n0 + wc * 64 + j * 16 + lr;
                                kc[(((size_t)b * NH + (col >> 6)) * SEQ + c) * DKH + (col & 63)] =
                                    f2b(acc[i][j][r]);
                            }
                        } else {
                            int vt = (c & ~63) | ((c & 15) * 4 + ((c >> 4) & 3));  // sigma^-1
#pragma unroll
                            for (int j = 0; j < 4; ++j) {
                                int col = n0 + wc * 64 + j * 16 + lr;
                                vtp[(((size_t)b * NH + (col >> 6)) * DKH + (col & 63)) * SEQ + vt] =
                                    f2b(acc[i][j][r]);
                            }
                        }
                    }
                }
            }
        }
    } else {
#pragma unroll
        for (int i = 0; i < 4; ++i)
#pragma unroll
            for (int j = 0; j < 4; ++j) {
                int col = n0 + wc * 64 + j * 16 + lr;
#pragma unroll
                for (int r = 0; r < 4; ++r) {
                    int row = m0 + wr * 64 + i * 16 + lg * 4 + r;
                    of[(size_t)row * GN + col] = acc[i][j][r];
                }
            }
    }
}

// Flash attention over compacted keys (unchanged, passing).
__global__ __launch_bounds__(256)
void attn_kernel(ushort* __restrict__ ws, const int* __restrict__ mbuf)
{
    const int bid = blockIdx.x;
    const int qt = bid & 31;
    const int h  = (bid >> 5) & 15;
    const int b  = bid >> 9;
    const int bh = b * NH + h;

    const ushort* Qp = ws + OFF_QH + (size_t)bh * (SEQ * DKH);
    const ushort* Kc = ws + OFF_KC + (size_t)bh * (SEQ * DKH);
    const ushort* VT = ws + OFF_VT + (size_t)bh * (DKH * SEQ);
    ushort* At = ws + OFF_AT;

    const int mb = mbuf[b];
    const int nt = (mb + 63) >> 6;

    __shared__ __align__(16) ushort lK[2][64 * 64];
    __shared__ __align__(16) ushort lV[2][64 * 64];
    __shared__ __align__(16) ushort lP[4][16][72];

    const int tid = threadIdx.x;
    const int lane = tid & 63, wid = tid >> 6;
    const int lr = lane & 15, lg = lane >> 4;
    ushort* lPw = &lP[wid][0][0];

    const int srow = wid * 16 + (lane >> 3);
    const int sg = lane & 7;

    const int qrow0 = qt * 64 + wid * 16;
    bf16x8 qf[2];
#pragma unroll
    for (int kk = 0; kk < 2; ++kk)
        qf[kk] = *(const bf16x8*)(Qp + (size_t)(qrow0 + lr) * DKH + kk * 32 + lg * 8);

    f32x4 acc_o[4] = {};
    float lrun[4] = {0.f, 0.f, 0.f, 0.f};

    auto STAGE = [&](int buf, int kt) {
        const int kbase = kt * 64;
#pragma unroll
        for (int c = 0; c < 2; ++c) {
            int r = srow + c * 8;
            gload_lds16(Kc + (size_t)(kbase + r) * DKH + ((sg ^ (r & 7)) * 8),
                        &lK[buf][(wid * 16 + c * 8) * 64]);
            gload_lds16(VT + (size_t)r * SEQ + kbase + ((sg ^ (r & 7)) * 8),
                        &lV[buf][(wid * 16 + c * 8) * 64]);
        }
    };

    STAGE(0, 0);
    __syncthreads();

    for (int kt = 0; kt < nt; ++kt) {
        const int cur = kt & 1;
        if (kt + 1 < nt) STAGE(cur ^ 1, kt + 1);
        const ushort* lKc = lK[cur];
        const ushort* lVc = lV[cur];

        f32x4 s[4];
        __builtin_amdgcn_s_setprio(1);
#pragma unroll
        for (int fc = 0; fc < 4; ++fc) {
            int row = fc * 16 + lr;
            int sw = row & 7;
            bf16x8 kf0 = *(const bf16x8*)(lKc + row * 64 + ((lg ^ sw) * 8));
            bf16x8 kf1 = *(const bf16x8*)(lKc + row * 64 + (((4 + lg) ^ sw) * 8));
            f32x4 t = {};
            t = __builtin_amdgcn_mfma_f32_16x16x32_bf16(qf[0], kf0, t, 0, 0, 0);
            t = __builtin_amdgcn_mfma_f32_16x16x32_bf16(qf[1], kf1, t, 0, 0, 0);
            s[fc] = t;
        }
        __builtin_amdgcn_s_setprio(0);

        if (kt == nt - 1) {
            const int kbase = kt * 64;
#pragma unroll
            for (int fc = 0; fc < 4; ++fc)
                if (kbase + fc * 16 + lr >= mb)
                    s[fc] = f32x4{NEGV, NEGV, NEGV, NEGV};
        }

#pragma unroll
        for (int r = 0; r < 4; ++r) {
            float p0 = EXP2(s[0][r]), p1 = EXP2(s[1][r]);
            float p2 = EXP2(s[2][r]), p3 = EXP2(s[3][r]);
            lrun[r] += (p0 + p1) + (p2 + p3);
            uint2 pk;
            pk.x = cvt_pk(p0, p1);
            pk.y = cvt_pk(p2, p3);
            *(uint2*)(lPw + (lg * 4 + r) * 72 + lr * 4) = pk;
        }

        __builtin_amdgcn_s_setprio(1);
#pragma unroll
        for (int kk = 0; kk < 2; ++kk) {
            bf16x8 pf = *(const bf16x8*)(lPw + lr * 72 + kk * 32 + lg * 8);
#pragma unroll
            for (int fc2 = 0; fc2 < 4; ++fc2) {
                int d = fc2 * 16 + lr;
                bf16x8 vf = *(const bf16x8*)(lVc + d * 64 + (((kk * 4 + lg) ^ (d & 7)) * 8));
                acc_o[fc2] = __builtin_amdgcn_mfma_f32_16x16x32_bf16(pf, vf, acc_o[fc2], 0, 0, 0);
            }
        }
        __builtin_amdgcn_s_setprio(0);
        __syncthreads();
    }

#pragma unroll
    for (int r = 0; r < 4; ++r) {
        float l = lrun[r];
        l += __shfl_xor(l, 1);
        l += __shfl_xor(l, 2);
        l += __shfl_xor(l, 4);
        l += __shfl_xor(l, 8);
        float rl = 1.0f / l;
        int qrow = qrow0 + lg * 4 + r;
#pragma unroll
        for (int fc2 = 0; fc2 < 4; ++fc2)
            At[((size_t)(b * SEQ) + qrow) * DM + h * DKH + fc2 * 16 + lr] =
                f2b(acc_o[fc2][r] * rl);
    }
}

extern "C" void kernel_launch(void* const* d_in, const int* in_sizes, int n_in,
                              void* d_out, int out_size, void* d_ws, size_t ws_size,
                              hipStream_t stream) {
    const float* kin = (const float*)d_in[0];
    const float* vin = (const float*)d_in[1];
    const float* qin = (const float*)d_in[2];
    const int*   msk = (const int*)d_in[3];
    const float* wq  = (const float*)d_in[4];
    const float* wk  = (const float*)d_in[5];
    const float* wv  = (const float*)d_in[6];
    const float* wo  = (const float*)d_in[7];
    ushort* ws = (ushort*)d_ws;
    float* out = (float*)d_out;
    int* cposb = (int*)d_out;          // d_out scratch: consumed before final GEMM writes
    int* mbuf = cposb + BS * SEQ;

    scan_kernel<<<2, 256, 0, stream>>>(msk, cposb, mbuf);
    gemm_fused<true><<<dim3(8, 32, 3), 256, 0, stream>>>(qin, kin, vin, wq, wk, wv, wo,
                                                         ws, nullptr, cposb);
    attn_kernel<<<1024, 256, 0, stream>>>(ws, mbuf);
    gemm_fused<false><<<dim3(8, 32, 1), 256, 0, stream>>>(qin, kin, vin, wq, wk, wv, wo,
                                                          ws, out, nullptr);
}

// Round 9
// 128.576 us; speedup vs baseline: 1.5251x; 1.5251x over previous
//
#include <hip/hip_runtime.h>

typedef __bf16 bf16x8 __attribute__((ext_vector_type(8)));
typedef float f32x4 __attribute__((ext_vector_type(4)));

#define BS 2
#define SEQ 2048
#define DM 1024
#define NH 16
#define DKH 64
#define GM 4096
#define GN 1024
#define GK 1024
#define NEGV (-1e9f)

#define OFF_XQ 0u
#define OFF_XK 4194304u
#define OFF_XV 8388608u
#define OFF_WQ 12582912u
#define OFF_WK 13631488u
#define OFF_WV 14680064u
#define OFF_WO 15728640u
#define OFF_QH 16777216u
#define OFF_KC 20971520u
#define OFF_VT 25165824u
#define OFF_AT OFF_XQ

#if __has_builtin(__builtin_amdgcn_exp2f)
#define EXP2(x) __builtin_amdgcn_exp2f(x)
#else
static __device__ __forceinline__ float EXP2(float x) {
    float r;
    asm volatile("v_exp_f32 %0, %1" : "=v"(r) : "v"(x));
    return r;
}
#endif

__device__ __forceinline__ unsigned cvt_pk(float lo, float hi) {
    unsigned r;
    asm volatile("v_cvt_pk_bf16_f32 %0, %1, %2" : "=v"(r) : "v"(lo), "v"(hi));
    return r;
}

__device__ __forceinline__ unsigned short f2b(float f) {
    unsigned u = __builtin_bit_cast(unsigned, f);
    u += 0x7fffu + ((u >> 16) & 1u);
    return (unsigned short)(u >> 16);
}

typedef const __attribute__((address_space(1))) unsigned int* gas_t;
typedef __attribute__((address_space(3))) unsigned int* las_t;

__device__ __forceinline__ void gload_lds16(const ushort* g, ushort* l) {
    __builtin_amdgcn_global_load_lds((gas_t)(const void*)g, (las_t)(void*)l, 16, 0, 0);
}

#define BARRIER() __builtin_amdgcn_s_barrier()
#define VMCNT(n) asm volatile("s_waitcnt vmcnt(" #n ")" ::: "memory")

__global__ __launch_bounds__(256)
void cvt_kernel(const float* __restrict__ q, const float* __restrict__ k,
                const float* __restrict__ v, const float* __restrict__ wq,
                const float* __restrict__ wk, const float* __restrict__ wv,
                const float* __restrict__ wo, ushort* __restrict__ ws)
{
    const float* src; unsigned n; unsigned dst;
    switch (blockIdx.y) {
        case 0: src = q;  n = 4194304u; dst = OFF_XQ; break;
        case 1: src = k;  n = 4194304u; dst = OFF_XK; break;
        case 2: src = v;  n = 4194304u; dst = OFF_XV; break;
        case 3: src = wq; n = 1048576u; dst = OFF_WQ; break;
        case 4: src = wk; n = 1048576u; dst = OFF_WK; break;
        case 5: src = wv; n = 1048576u; dst = OFF_WV; break;
        default: src = wo; n = 1048576u; dst = OFF_WO; break;
    }
    unsigned i = (blockIdx.x * 256u + threadIdx.x) * 4u;
    if (i >= n) return;
    float4 f = *(const float4*)(src + i);
    ushort4 o;
    o.x = f2b(f.x); o.y = f2b(f.y); o.z = f2b(f.z); o.w = f2b(f.w);
    *(ushort4*)(ws + dst + i) = o;
}

// Per-batch compaction: cpos[b][s] = compact index (or -1); mbuf[b] = count.
__global__ __launch_bounds__(256)
void scan_kernel(const int* __restrict__ mask, int* __restrict__ cpos, int* __restrict__ mbuf)
{
    const int b = blockIdx.x;
    const int* mp = mask + (size_t)b * SEQ;
    const int tid = threadIdx.x;
    const int lane = tid & 63, w = tid >> 6;
    int v[8];
    int cnt = 0;
#pragma unroll
    for (int j = 0; j < 8; ++j) { v[j] = mp[tid * 8 + j]; cnt += (v[j] != 0); }
    int inc = cnt;
#pragma unroll
    for (int d = 1; d < 64; d <<= 1) {
        int t = __shfl_up(inc, d);
        if (lane >= d) inc += t;
    }
    __shared__ int wsum[4];
    if (lane == 63) wsum[w] = inc;
    __syncthreads();
    int base = inc - cnt;
    for (int i = 0; i < w; ++i) base += wsum[i];
    int c = base;
    int* ob = cpos + (size_t)b * SEQ;
#pragma unroll
    for (int j = 0; j < 8; ++j) {
        ob[tid * 8 + j] = (v[j] != 0) ? c : -1;
        c += (v[j] != 0);
    }
    if (tid == 255) mbuf[b] = base + cnt;
}

// ---------------- 256x256 8-phase projection GEMM (round-7, best) ----------------
__global__ __launch_bounds__(512)
void gemm256(const ushort* __restrict__ Abase, const ushort* __restrict__ Bbase,
             ushort* __restrict__ wsbase, const int* __restrict__ cpos)
{
    __shared__ __align__(16) ushort lA[2][2][8192];  // [slot][half(128r)][128*64]
    __shared__ __align__(16) ushort lB[2][2][8192];

    const unsigned z = blockIdx.z;
    const ushort* A  = Abase + (size_t)z * (GM * GK);
    const ushort* Bw = Bbase + (size_t)z * (GN * GK);
    const float scale = (z == 0) ? 0.125f * 1.44269504088896f : 1.0f;

    const int tid = threadIdx.x;
    const int lane = tid & 63, wid = tid >> 6;
    const int wr = wid >> 2, wc = wid & 3;
    const int lr = lane & 15, lg = lane >> 4;
    const int srow8 = lane >> 3, scol = lane & 7;

    const int lin = blockIdx.y * 4 + blockIdx.x;
    const int xcd = lin & 7, kidx = lin >> 3;
    const int m0 = (xcd * 2 + (kidx >> 2)) * 256;
    const int n0 = (kidx & 3) * 256;

    f32x4 acc[8][4] = {};
    bf16x8 aq[4][2], aq2[4][2], b01[2][2], b23[2][2];

#define STAGE_A(s, h, t)                                                          \
    _Pragma("unroll") for (int c = 0; c < 2; ++c) {                               \
        int rih = (wid * 2 + c) * 8 + srow8;                                      \
        gload_lds16(A + (size_t)(m0 + (h) * 128 + rih) * GK + (t) * 64 +          \
                        ((scol ^ (rih & 7)) * 8),                                 \
                    &lA[s][h][(wid * 2 + c) * 512]);                              \
    }
#define STAGE_B(s, h, t)                                                          \
    _Pragma("unroll") for (int c = 0; c < 2; ++c) {                               \
        int rih = (wid * 2 + c) * 8 + srow8;                                      \
        gload_lds16(Bw + (size_t)(n0 + (h) * 128 + rih) * GK + (t) * 64 +         \
                         ((scol ^ (rih & 7)) * 8),                                \
                    &lB[s][h][(wid * 2 + c) * 512]);                              \
    }
#define LDA_FRAG(dst, s, ibase)                                                   \
    _Pragma("unroll") for (int i2 = 0; i2 < 4; ++i2)                              \
    _Pragma("unroll") for (int kk = 0; kk < 2; ++kk) {                            \
        int row = ((ibase) + i2) * 16 + lr;                                       \
        dst[i2][kk] = *(const bf16x8*)&lA[s][wr][row * 64 +                       \
                          (((kk * 4 + lg) ^ (row & 7)) * 8)];                     \
    }
#define LDB_FRAG(dst, s, jbase)                                                   \
    _Pragma("unroll") for (int j2 = 0; j2 < 2; ++j2)                              \
    _Pragma("unroll") for (int kk = 0; kk < 2; ++kk) {                            \
        int row = (wc & 1) * 64 + ((jbase) + j2) * 16 + lr;                       \
        dst[j2][kk] = *(const bf16x8*)&lB[s][wc >> 1][row * 64 +                  \
                          (((kk * 4 + lg) ^ (row & 7)) * 8)];                     \
    }
#define MMA_Q(ibase, jbase, av, bv)                                               \
    __builtin_amdgcn_s_setprio(1);                                                \
    _Pragma("unroll") for (int i2 = 0; i2 < 4; ++i2)                              \
    _Pragma("unroll") for (int j2 = 0; j2 < 2; ++j2)                              \
    _Pragma("unroll") for (int kk = 0; kk < 2; ++kk)                              \
        acc[(ibase) + i2][(jbase) + j2] = __builtin_amdgcn_mfma_f32_16x16x32_bf16(\
            av[i2][kk], bv[j2][kk], acc[(ibase) + i2][(jbase) + j2], 0, 0, 0);    \
    __builtin_amdgcn_s_setprio(0);

    STAGE_B(0, 0, 0); STAGE_B(0, 1, 0); STAGE_A(0, 0, 0); STAGE_A(0, 1, 0);
    STAGE_B(1, 0, 1); STAGE_B(1, 1, 1); STAGE_A(1, 0, 1); STAGE_A(1, 1, 1);
    VMCNT(8);
    BARRIER();

    for (int it = 0; it < 7; ++it) {
        const int t2 = 2 * it + 2, t3 = 2 * it + 3;
        LDA_FRAG(aq, 0, 0); LDB_FRAG(b01, 0, 0);
        BARRIER(); MMA_Q(0, 0, aq, b01); BARRIER();
        LDB_FRAG(b23, 0, 2);
        BARRIER(); MMA_Q(0, 2, aq, b23); BARRIER();
        LDA_FRAG(aq2, 0, 4);
        STAGE_B(0, 0, t2); STAGE_B(0, 1, t2);
        BARRIER(); MMA_Q(4, 2, aq2, b23); BARRIER();
        STAGE_A(0, 0, t2);
        VMCNT(6);
        BARRIER(); MMA_Q(4, 0, aq2, b01); BARRIER();
        LDA_FRAG(aq, 1, 0); LDB_FRAG(b01, 1, 0);
        STAGE_A(0, 1, t2);
        BARRIER(); MMA_Q(0, 0, aq, b01); BARRIER();
        LDB_FRAG(b23, 1, 2);
        BARRIER(); MMA_Q(0, 2, aq, b23); BARRIER();
        LDA_FRAG(aq2, 1, 4);
        STAGE_B(1, 0, t3); STAGE_B(1, 1, t3);
        BARRIER(); MMA_Q(4, 2, aq2, b23); BARRIER();
        STAGE_A(1, 0, t3); STAGE_A(1, 1, t3);
        VMCNT(8);
        BARRIER(); MMA_Q(4, 0, aq2, b01); BARRIER();
    }

    LDA_FRAG(aq, 0, 0); LDB_FRAG(b01, 0, 0);
    BARRIER(); MMA_Q(0, 0, aq, b01); BARRIER();
    LDB_FRAG(b23, 0, 2);
    BARRIER(); MMA_Q(0, 2, aq, b23); BARRIER();
    LDA_FRAG(aq2, 0, 4);
    BARRIER(); MMA_Q(4, 2, aq2, b23); BARRIER();
    VMCNT(0);
    BARRIER(); MMA_Q(4, 0, aq2, b01); BARRIER();
    LDA_FRAG(aq, 1, 0); LDB_FRAG(b01, 1, 0);
    BARRIER(); MMA_Q(0, 0, aq, b01); BARRIER();
    LDB_FRAG(b23, 1, 2);
    BARRIER(); MMA_Q(0, 2, aq, b23); BARRIER();
    LDA_FRAG(aq2, 1, 4);
    BARRIER(); MMA_Q(4, 2, aq2, b23); BARRIER();
    BARRIER(); MMA_Q(4, 0, aq2, b01); BARRIER();

    ushort* qh  = wsbase + OFF_QH;
    ushort* kc  = wsbase + OFF_KC;
    ushort* vtp = wsbase + OFF_VT;
#pragma unroll
    for (int i = 0; i < 8; ++i) {
#pragma unroll
        for (int r = 0; r < 4; ++r) {
            int row = m0 + wr * 128 + i * 16 + lg * 4 + r;
            int b = row >> 11, s = row & 2047;
            if (z == 0) {
#pragma unroll
                for (int j = 0; j < 4; ++j) {
                    int col = n0 + wc * 64 + j * 16 + lr;
                    qh[(((size_t)b * NH + (col >> 6)) * SEQ + s) * DKH + (col & 63)] =
                        f2b(acc[i][j][r] * scale);
                }
            } else {
                int c = cpos[b * SEQ + s];
                if (c >= 0) {
                    if (z == 1) {
#pragma unroll
                        for (int j = 0; j < 4; ++j) {
                            int col = n0 + wc * 64 + j * 16 + lr;
                            kc[(((size_t)b * NH + (col >> 6)) * SEQ + c) * DKH + (col & 63)] =
                                f2b(acc[i][j][r]);
                        }
                    } else {
                        int vt = (c & ~63) | ((c & 15) * 4 + ((c >> 4) & 3));  // sigma^-1
#pragma unroll
                        for (int j = 0; j < 4; ++j) {
                            int col = n0 + wc * 64 + j * 16 + lr;
                            vtp[(((size_t)b * NH + (col >> 6)) * DKH + (col & 63)) * SEQ + vt] =
                                f2b(acc[i][j][r]);
                        }
                    }
                }
            }
        }
    }
#undef STAGE_A
#undef STAGE_B
#undef LDA_FRAG
#undef LDB_FRAG
#undef MMA_Q
}

// Final output projection: C = A @ B^T, fp32 out. m97 128-square structure.
__global__ __launch_bounds__(256)
void gemm_bt(const ushort* __restrict__ A, const ushort* __restrict__ Bw,
             float* __restrict__ of)
{
    __shared__ __align__(16) ushort lA[128 * 64];
    __shared__ __align__(16) ushort lB[128 * 64];

    const int tid = threadIdx.x;
    const int lane = tid & 63, wid = tid >> 6;
    const int wr = wid >> 1, wc = wid & 1;
    const int lr = lane & 15, lg = lane >> 4;
    const int lin = blockIdx.y * 8 + blockIdx.x;
    const int swz = (lin & 7) * 32 + (lin >> 3);
    const int m0 = (swz >> 3) * 128, n0 = (swz & 7) * 128;
    const int srow = wid * 32 + (lane >> 3);
    const int scol = (lane & 7) * 8;

    f32x4 acc[4][4] = {};

    for (int k0 = 0; k0 < GK; k0 += 64) {
        __syncthreads();
#pragma unroll
        for (int p = 0; p < 4; ++p) {
            gload_lds16(A + (size_t)(m0 + srow + p * 8) * GK + k0 + scol,
                        &lA[(wid * 32 + p * 8) * 64]);
            gload_lds16(Bw + (size_t)(n0 + srow + p * 8) * GK + k0 + scol,
                        &lB[(wid * 32 + p * 8) * 64]);
        }
        __syncthreads();
#pragma unroll
        for (int kk = 0; kk < 2; ++kk) {
            bf16x8 af[4], bfr[4];
#pragma unroll
            for (int i = 0; i < 4; ++i) {
                af[i]  = *(const bf16x8*)(&lA[(wr * 64 + i * 16 + lr) * 64 + kk * 32 + lg * 8]);
                bfr[i] = *(const bf16x8*)(&lB[(wc * 64 + i * 16 + lr) * 64 + kk * 32 + lg * 8]);
            }
#pragma unroll
            for (int i = 0; i < 4; ++i)
#pragma unroll
                for (int j = 0; j < 4; ++j)
                    acc[i][j] = __builtin_amdgcn_mfma_f32_16x16x32_bf16(af[i], bfr[j], acc[i][j], 0, 0, 0);
        }
    }

#pragma unroll
    for (int i = 0; i < 4; ++i)
#pragma unroll
        for (int j = 0; j < 4; ++j) {
            int col = n0 + wc * 64 + j * 16 + lr;
#pragma unroll
            for (int r = 0; r < 4; ++r) {
                int row = m0 + wr * 64 + i * 16 + lg * 4 + r;
                of[(size_t)row * GN + col] = acc[i][j][r];
            }
        }
}

// Flash attention over compacted keys, QBLK=128 (4 waves x 32 q-rows, 2 row-frags).
// KV tile = 64 compact keys, double-buffered gload_lds with XOR-swizzle.
__global__ __launch_bounds__(256)
void attn_kernel(ushort* __restrict__ ws, const int* __restrict__ mbuf)
{
    const int bid = blockIdx.x;
    const int qt = bid & 15;
    const int h  = (bid >> 4) & 15;
    const int b  = bid >> 8;
    const int bh = b * NH + h;

    const ushort* Qp = ws + OFF_QH + (size_t)bh * (SEQ * DKH);
    const ushort* Kc = ws + OFF_KC + (size_t)bh * (SEQ * DKH);
    const ushort* VT = ws + OFF_VT + (size_t)bh * (DKH * SEQ);
    ushort* At = ws + OFF_AT;

    const int mb = mbuf[b];
    const int nt = (mb + 63) >> 6;

    __shared__ __align__(16) ushort lK[2][64 * 64];
    __shared__ __align__(16) ushort lV[2][64 * 64];
    __shared__ __align__(16) ushort lP[4][32][72];

    const int tid = threadIdx.x;
    const int lane = tid & 63, wid = tid >> 6;
    const int lr = lane & 15, lg = lane >> 4;
    ushort* lPw = &lP[wid][0][0];

    const int srow = wid * 16 + (lane >> 3);
    const int sg = lane & 7;

    const int qrow0 = qt * 128 + wid * 32;
    bf16x8 qf[2][2];
#pragma unroll
    for (int fr = 0; fr < 2; ++fr)
#pragma unroll
        for (int kk = 0; kk < 2; ++kk)
            qf[fr][kk] = *(const bf16x8*)(Qp + (size_t)(qrow0 + fr * 16 + lr) * DKH + kk * 32 + lg * 8);

    f32x4 acc_o[2][4] = {};
    float lrun[2][4] = {};

    auto STAGE = [&](int buf, int kt) {
        const int kbase = kt * 64;
#pragma unroll
        for (int c = 0; c < 2; ++c) {
            int r = srow + c * 8;
            gload_lds16(Kc + (size_t)(kbase + r) * DKH + ((sg ^ (r & 7)) * 8),
                        &lK[buf][(wid * 16 + c * 8) * 64]);
            gload_lds16(VT + (size_t)r * SEQ + kbase + ((sg ^ (r & 7)) * 8),
                        &lV[buf][(wid * 16 + c * 8) * 64]);
        }
    };

    STAGE(0, 0);
    __syncthreads();

    for (int kt = 0; kt < nt; ++kt) {
        const int cur = kt & 1;
        if (kt + 1 < nt) STAGE(cur ^ 1, kt + 1);
        const ushort* lKc = lK[cur];
        const ushort* lVc = lV[cur];

        // S = Q K^T  (keys = compact fc*16+lr)
        f32x4 s[2][4];
        __builtin_amdgcn_s_setprio(1);
#pragma unroll
        for (int fc = 0; fc < 4; ++fc) {
            int row = fc * 16 + lr;
            int sw = row & 7;
            bf16x8 kf0 = *(const bf16x8*)(lKc + row * 64 + ((lg ^ sw) * 8));
            bf16x8 kf1 = *(const bf16x8*)(lKc + row * 64 + (((4 + lg) ^ sw) * 8));
#pragma unroll
            for (int fr = 0; fr < 2; ++fr) {
                f32x4 t = {};
                t = __builtin_amdgcn_mfma_f32_16x16x32_bf16(qf[fr][0], kf0, t, 0, 0, 0);
                t = __builtin_amdgcn_mfma_f32_16x16x32_bf16(qf[fr][1], kf1, t, 0, 0, 0);
                s[fr][fc] = t;
            }
        }
        __builtin_amdgcn_s_setprio(0);

        if (kt == nt - 1) {
            const int kbase = kt * 64;
#pragma unroll
            for (int fc = 0; fc < 4; ++fc)
                if (kbase + fc * 16 + lr >= mb)
#pragma unroll
                    for (int fr = 0; fr < 2; ++fr)
                        s[fr][fc] = f32x4{NEGV, NEGV, NEGV, NEGV};
        }

        // softmax (fixed max): p = 2^s; pack P sigma-permuted (pos = lr*4+fc)
#pragma unroll
        for (int fr = 0; fr < 2; ++fr)
#pragma unroll
            for (int r = 0; r < 4; ++r) {
                float p0 = EXP2(s[fr][0][r]), p1 = EXP2(s[fr][1][r]);
                float p2 = EXP2(s[fr][2][r]), p3 = EXP2(s[fr][3][r]);
                lrun[fr][r] += (p0 + p1) + (p2 + p3);
                uint2 pk;
                pk.x = cvt_pk(p0, p1);
                pk.y = cvt_pk(p2, p3);
                *(uint2*)(lPw + (fr * 16 + lg * 4 + r) * 72 + lr * 4) = pk;
            }

        // O += P @ V  (contraction over sigma positions)
        __builtin_amdgcn_s_setprio(1);
#pragma unroll
        for (int kk = 0; kk < 2; ++kk) {
            bf16x8 pf[2];
#pragma unroll
            for (int fr = 0; fr < 2; ++fr)
                pf[fr] = *(const bf16x8*)(lPw + (fr * 16 + lr) * 72 + kk * 32 + lg * 8);
#pragma unroll
            for (int fc2 = 0; fc2 < 4; ++fc2) {
                int d = fc2 * 16 + lr;
                bf16x8 vf = *(const bf16x8*)(lVc + d * 64 + (((kk * 4 + lg) ^ (d & 7)) * 8));
#pragma unroll
                for (int fr = 0; fr < 2; ++fr)
                    acc_o[fr][fc2] = __builtin_amdgcn_mfma_f32_16x16x32_bf16(pf[fr], vf, acc_o[fr][fc2], 0, 0, 0);
            }
        }
        __builtin_amdgcn_s_setprio(0);
        __syncthreads();
    }

    // epilogue: reduce row-sums across lr, divide, write concat bf16
#pragma unroll
    for (int fr = 0; fr < 2; ++fr)
#pragma unroll
        for (int r = 0; r < 4; ++r) {
            float l = lrun[fr][r];
            l += __shfl_xor(l, 1);
            l += __shfl_xor(l, 2);
            l += __shfl_xor(l, 4);
            l += __shfl_xor(l, 8);
            float rl = 1.0f / l;
            int qrow = qrow0 + fr * 16 + lg * 4 + r;
#pragma unroll
            for (int fc2 = 0; fc2 < 4; ++fc2)
                At[((size_t)(b * SEQ) + qrow) * DM + h * DKH + fc2 * 16 + lr] =
                    f2b(acc_o[fr][fc2][r] * rl);
        }
}

extern "C" void kernel_launch(void* const* d_in, const int* in_sizes, int n_in,
                              void* d_out, int out_size, void* d_ws, size_t ws_size,
                              hipStream_t stream) {
    const float* kin = (const float*)d_in[0];
    const float* vin = (const float*)d_in[1];
    const float* qin = (const float*)d_in[2];
    const int*   msk = (const int*)d_in[3];
    const float* wq  = (const float*)d_in[4];
    const float* wk  = (const float*)d_in[5];
    const float* wv  = (const float*)d_in[6];
    const float* wo  = (const float*)d_in[7];
    ushort* ws = (ushort*)d_ws;
    float* out = (float*)d_out;
    int* cposb = (int*)d_out;          // d_out scratch: consumed before final GEMM writes
    int* mbuf = cposb + BS * SEQ;

    scan_kernel<<<2, 256, 0, stream>>>(msk, cposb, mbuf);
    cvt_kernel<<<dim3(4096, 7), 256, 0, stream>>>(qin, kin, vin, wq, wk, wv, wo, ws);
    gemm256<<<dim3(4, 16, 3), 512, 0, stream>>>(ws + OFF_XQ, ws + OFF_WQ, ws, cposb);
    attn_kernel<<<512, 256, 0, stream>>>(ws, mbuf);
    gemm_bt<<<dim3(8, 32), 256, 0, stream>>>(ws + OFF_AT, ws + OFF_WO, out);
}